// Round 7
// baseline (599.869 us; speedup 1.0000x reference)
//
#include <hip/hip_runtime.h>
#include <hip/hip_bf16.h>

#define Bb 2
#define Ss 4096
#define Dd 512
#define Hh 8
#define DHh 64

typedef __attribute__((ext_vector_type(8))) short short8;
typedef __attribute__((ext_vector_type(4))) float floatx4;

static __device__ __forceinline__ ushort bfbits(float f) {
  union { __hip_bfloat16 h; ushort u; } cv;
  cv.h = __float2bfloat16(f);
  return cv.u;
}

// pack two fp32 -> two bf16 (truncation; P-weights only, 2^-8 rel err)
static __device__ __forceinline__ unsigned int packhi(float a, float b) {
  union { float f; unsigned int u; } ca, cb; ca.f = a; cb.f = b;
  return (ca.u >> 16) | (cb.u & 0xffff0000u);
}

// ---------------- merged fp32 -> bf16: [x | Wq | Wk | Wv | Wo] ----------------
__global__ void cvt_all(const float* __restrict__ x,
                        const float* __restrict__ w0, const float* __restrict__ w1,
                        const float* __restrict__ w2, const float* __restrict__ w3,
                        ushort* __restrict__ out) {
  const int XN4 = (Bb * Ss * Dd) / 4;
  const int WN4 = (Dd * Dd) / 4;        // 65,536 = 2^16
  int i = blockIdx.x * blockDim.x + threadIdx.x;
  if (i >= XN4 + 4 * WN4) return;
  const float* s; int li;
  if (i < XN4) { s = x; li = i; }
  else {
    int t = i - XN4; int j = t >> 16; li = t & (WN4 - 1);
    s = (j == 0) ? w0 : (j == 1) ? w1 : (j == 2) ? w2 : w3;
  }
  float4 f = ((const float4*)s)[li];
  ushort4 u;
  u.x = bfbits(f.x); u.y = bfbits(f.y); u.z = bfbits(f.z); u.w = bfbits(f.w);
  ((ushort4*)out)[i] = u;
}

// permuted V^T position: key s -> within-64 slot so flash PV A-frags are
// single contiguous 16B loads.
static __device__ __forceinline__ int vperm(int s0) {  // s0 multiple of 4
  int kb = (s0 >> 4) & 3, gq = (s0 >> 2) & 3;
  return (s0 & ~63) | ((kb >> 1) << 5) | (gq << 3) | ((kb & 1) << 2);
}

// ---------------- fused QKV projection GEMM ----------------
// Wave computes 64x64 (4x4 MFMA tiles): 8 loads per 16 MFMAs per K-step-32.
#define LDQK(buf, k0)                                                          \
  _Pragma("unroll")                                                            \
  for (int rb = 0; rb < 4; ++rb)                                               \
    af[buf][rb] = *(const short8*)(ap + (size_t)rb * 16 * 512 + (k0));         \
  _Pragma("unroll")                                                            \
  for (int cb = 0; cb < 4; ++cb)                                               \
    bf[buf][cb] = *(const short8*)(bp + (size_t)cb * 16 * 512 + (k0));

__global__ __launch_bounds__(256) void qkv_gemm(
    const ushort* __restrict__ xb,
    const ushort* __restrict__ Wq, const ushort* __restrict__ Wk, const ushort* __restrict__ Wv,
    const float* __restrict__ bq, const float* __restrict__ bk, const float* __restrict__ bv,
    ushort* __restrict__ qo, ushort* __restrict__ ko, ushort* __restrict__ vo)
{
  int mb = blockIdx.x / 12, rest = blockIdx.x % 12;
  int which = rest >> 2, nb = rest & 3;
  const ushort* Bw  = (which == 0) ? Wq : (which == 1) ? Wk : Wv;
  const float* bias = (which == 0) ? bq : (which == 1) ? bk : bv;
  int lane = threadIdx.x & 63, w = threadIdx.x >> 6;
  int wr = w & 1, wc = w >> 1;
  int g = lane >> 4, ln = lane & 15;
  int m0 = mb * 128 + wr * 64;
  int c0 = nb * 128 + wc * 64;
  const ushort* ap = xb + (size_t)(m0 + ln) * 512 + g * 8;
  const ushort* bp = Bw + (size_t)(c0 + ln) * 512 + g * 8;
  floatx4 acc[4][4] = {};
  short8 af[2][4], bf[2][4];
  LDQK(0, 0)
#pragma unroll
  for (int it = 0; it < 16; ++it) {
    int cur = it & 1;
    if (it < 15) { LDQK(cur ^ 1, (it + 1) * 32) }
#pragma unroll
    for (int rb = 0; rb < 4; ++rb)
#pragma unroll
      for (int cb = 0; cb < 4; ++cb)
        acc[rb][cb] = __builtin_amdgcn_mfma_f32_16x16x32_bf16(af[cur][rb], bf[cur][cb], acc[rb][cb], 0, 0, 0);
  }
  // q scale folds 1/sqrt(DH)=0.125 AND log2(e) so flash can use native exp2
  float scale = (which == 0) ? 0.125f * 1.44269504f : 1.0f;
#pragma unroll
  for (int rb = 0; rb < 4; ++rb)
#pragma unroll
    for (int cb = 0; cb < 4; ++cb) {
      int col = c0 + cb * 16 + ln;
      float bv_ = bias[col];
      int hh = col >> 6, dh = col & 63;
      if (which == 2) {
        int i0 = m0 + rb * 16 + g * 4;
        int bI = i0 >> 12, s0 = i0 & (Ss - 1);
        ushort4 pk;
        pk.x = bfbits(acc[rb][cb][0] + bv_);
        pk.y = bfbits(acc[rb][cb][1] + bv_);
        pk.z = bfbits(acc[rb][cb][2] + bv_);
        pk.w = bfbits(acc[rb][cb][3] + bv_);
        *(ushort4*)(vo + (((size_t)bI * Hh + hh) * DHh + dh) * Ss + vperm(s0)) = pk;
      } else {
        ushort* outp = (which == 0) ? qo : ko;
#pragma unroll
        for (int r = 0; r < 4; ++r) {
          int i = m0 + rb * 16 + g * 4 + r;
          int bI = i >> 12, s = i & (Ss - 1);
          outp[(((size_t)bI * Hh + hh) * Ss + s) * DHh + dh] = bfbits((acc[rb][cb][r] + bv_) * scale);
        }
      }
    }
}

// ---------------- output projection GEMM (fp32 out) ----------------
#define LD32(buf, k0)                                                          \
  af[buf][0] = *(const short8*)(ap + (k0));                                    \
  af[buf][1] = *(const short8*)(ap + 16 * 512 + (k0));                         \
  _Pragma("unroll")                                                            \
  for (int ns = 0; ns < 4; ++ns)                                               \
    bfr[buf][ns] = *(const short8*)(bp + (size_t)ns * 16 * 512 + (k0));

__global__ __launch_bounds__(256) void gemm_out(
    const ushort* __restrict__ A, const ushort* __restrict__ Bw,
    const float* __restrict__ bias, float* __restrict__ outp)
{
  int mb = blockIdx.x >> 3, nb = blockIdx.x & 7;
  int lane = threadIdx.x & 63, w = threadIdx.x >> 6;
  int g = lane >> 4, ln = lane & 15;
  int m0 = mb * 128 + w * 32;
  const ushort* ap = A + (size_t)(m0 + ln) * 512 + g * 8;
  const ushort* bp = Bw + (size_t)(nb * 64 + ln) * 512 + g * 8;
  floatx4 acc[2][4] = {};
  short8 af[2][2], bfr[2][4];
  LD32(0, 0)
#pragma unroll
  for (int it = 0; it < 16; ++it) {
    int cur = it & 1;
    if (it < 15) { LD32(cur ^ 1, (it + 1) * 32) }
#pragma unroll
    for (int ns = 0; ns < 4; ++ns) {
      acc[0][ns] = __builtin_amdgcn_mfma_f32_16x16x32_bf16(af[cur][0], bfr[cur][ns], acc[0][ns], 0, 0, 0);
      acc[1][ns] = __builtin_amdgcn_mfma_f32_16x16x32_bf16(af[cur][1], bfr[cur][ns], acc[1][ns], 0, 0, 0);
    }
  }
#pragma unroll
  for (int rb = 0; rb < 2; ++rb)
#pragma unroll
    for (int ns = 0; ns < 4; ++ns) {
      int col = nb * 64 + ns * 16 + ln;
      float bv_ = bias[col];
#pragma unroll
      for (int r = 0; r < 4; ++r)
        outp[(size_t)(m0 + rb * 16 + g * 4 + r) * 512 + col] = acc[rb][ns][r] + bv_;
    }
}

// ---------------- flash attention v7 ----------------
// 1024 blocks x 4 waves = 4 waves/SIMD (the R6 limiter was 2/SIMD).
// Block (bh,tq) runs q-tile t=tq then t=127-tq (work sums to 65 tiles/block);
// within a rep ALL 4 waves process the same q-tile, splitting keys into
// quarters -> identical K/V/Q lines per tile (L1 reuse), 4-way LDS-add merge.
// No-max softmax in exp2 domain (log2e folded into q scale).
__global__ __launch_bounds__(256, 4) void flash7(
    const ushort* __restrict__ q, const ushort* __restrict__ k,
    const ushort* __restrict__ vt, const float* __restrict__ gamma,
    ushort* __restrict__ o)
{
  __shared__ __align__(16) float Pmrg[3][64][34];   // waves 1..3 partial O + l
  __shared__ __align__(16) ushort Tb[16 * 72];      // store-transpose buffer

  int z = blockIdx.x;
  int bh = z & 15, tq = z >> 4;          // tq 0..63
  int b = bh >> 3, hh = bh & 7;
  int tid = threadIdx.x;
  int wv = tid >> 6, lane = tid & 63;
  int g = lane >> 4, ln = lane & 15;

  const ushort* kp = k + ((size_t)bh * Ss + ln) * DHh + g * 8;
  const ushort* vp = vt + ((size_t)bh * DHh + ln) * Ss + g * 8;

#pragma unroll 1
  for (int rep = 0; rep < 2; ++rep) {
    int t = rep ? (127 - tq) : tq;
    int q0 = t * 32;
    int nkt = (t >> 1) + 1;
    int ktm = nkt - 1;
    int lo = (nkt * wv) >> 2, hi = (nkt * (wv + 1)) >> 2;

    const ushort* qp = q + ((size_t)bh * Ss + q0 + ln) * DHh + g * 8;
    short8 qf00 = *(const short8*)qp;
    short8 qf01 = *(const short8*)(qp + 32);
    short8 qf10 = *(const short8*)(qp + 16 * DHh);
    short8 qf11 = *(const short8*)(qp + 16 * DHh + 32);

    int qrow0 = q0 + ln, qrow1 = q0 + 16 + ln;
    float gm0 = gamma[(size_t)b * Ss + qrow0];
    float gm1 = gamma[(size_t)b * Ss + qrow1];
    float l2[2] = {0.0f, 0.0f};
    floatx4 oacc[2][4] = {};

    short8 kfl[4], kfh[4], vf[8];
    int kb0 = lo * 64;
#pragma unroll
    for (int ns = 0; ns < 4; ++ns) {
      kfl[ns] = *(const short8*)(kp + (size_t)(kb0 + ns * 16) * DHh);
      kfh[ns] = *(const short8*)(kp + (size_t)(kb0 + ns * 16) * DHh + 32);
    }
#pragma unroll
    for (int cc = 0; cc < 8; ++cc)
      vf[cc] = *(const short8*)(vp + (size_t)((cc & 3) * 16) * Ss + kb0 + (cc >> 2) * 32);

    for (int kt = lo; kt < hi; ++kt) {
      int kbase = kt * 64;
      // ---- S^T = K . Q^T : 16 MFMAs ----
      float sv[2][16];
#pragma unroll
      for (int ns = 0; ns < 4; ++ns) {
        floatx4 z0 = {}, z1 = {};
        z0 = __builtin_amdgcn_mfma_f32_16x16x32_bf16(kfl[ns], qf00, z0, 0, 0, 0);
        z0 = __builtin_amdgcn_mfma_f32_16x16x32_bf16(kfh[ns], qf01, z0, 0, 0, 0);
        z1 = __builtin_amdgcn_mfma_f32_16x16x32_bf16(kfl[ns], qf10, z1, 0, 0, 0);
        z1 = __builtin_amdgcn_mfma_f32_16x16x32_bf16(kfh[ns], qf11, z1, 0, 0, 0);
#pragma unroll
        for (int r = 0; r < 4; ++r) { sv[0][ns * 4 + r] = z0[r]; sv[1][ns * 4 + r] = z1[r]; }
      }
      // ---- prefetch next K tile ----
      if (kt + 1 < hi) {
        const ushort* kn = kp + (size_t)(kbase + 64) * DHh;
#pragma unroll
        for (int ns = 0; ns < 4; ++ns) {
          kfl[ns] = *(const short8*)(kn + (size_t)(ns * 16) * DHh);
          kfh[ns] = *(const short8*)(kn + (size_t)(ns * 16) * DHh + 32);
        }
      }
      // ---- weights: p = exp2(s) / (1 + gm*max(i-j,0)); s already in log2 ----
      bool last = (kt == ktm);
      short8 pfrag[2][2];
#pragma unroll
      for (int qb = 0; qb < 2; ++qb) {
        int qrow = qb ? qrow1 : qrow0;
        float gm = qb ? gm1 : gm0;
        int db = qrow - kbase - g * 4;     // delta = db - ns*16 - r
        float fd = (float)db;
        float rs = 0.0f;
        if (last) {
#pragma unroll
          for (int e = 0; e < 16; ++e)
            if (db - (e >> 2) * 16 - (e & 3) < 0) sv[qb][e] = -1e30f;
#pragma unroll
          for (int e = 0; e < 16; ++e) {
            float delta = fmaxf(fd - (float)((e >> 2) * 16 + (e & 3)), 0.0f);
            float wt = __builtin_amdgcn_rcpf(fmaf(gm, delta, 1.0f));
            float pv = __builtin_amdgcn_exp2f(sv[qb][e]) * wt;
            rs += pv;
            sv[qb][e] = pv;
          }
        } else {
          // kt < ktm: delta >= 1 always, no clamp/mask needed
#pragma unroll
          for (int e = 0; e < 16; ++e) {
            float delta = fd - (float)((e >> 2) * 16 + (e & 3));
            float wt = __builtin_amdgcn_rcpf(fmaf(gm, delta, 1.0f));
            float pv = __builtin_amdgcn_exp2f(sv[qb][e]) * wt;
            rs += pv;
            sv[qb][e] = pv;
          }
        }
        l2[qb] += rs;
#pragma unroll
        for (int c = 0; c < 2; ++c) {
          uint4 pkd;
          pkd.x = packhi(sv[qb][8 * c + 0], sv[qb][8 * c + 1]);
          pkd.y = packhi(sv[qb][8 * c + 2], sv[qb][8 * c + 3]);
          pkd.z = packhi(sv[qb][8 * c + 4], sv[qb][8 * c + 5]);
          pkd.w = packhi(sv[qb][8 * c + 6], sv[qb][8 * c + 7]);
          pfrag[qb][c] = *(short8*)&pkd;
        }
      }
      // ---- PV: O^T += V^T . P^T : 16 MFMAs ----
#pragma unroll
      for (int c = 0; c < 2; ++c)
#pragma unroll
        for (int ds = 0; ds < 4; ++ds) {
          oacc[0][ds] = __builtin_amdgcn_mfma_f32_16x16x32_bf16(vf[c * 4 + ds], pfrag[0][c], oacc[0][ds], 0, 0, 0);
          oacc[1][ds] = __builtin_amdgcn_mfma_f32_16x16x32_bf16(vf[c * 4 + ds], pfrag[1][c], oacc[1][ds], 0, 0, 0);
        }
      // ---- prefetch next V tile ----
      if (kt + 1 < hi) {
#pragma unroll
        for (int cc = 0; cc < 8; ++cc)
          vf[cc] = *(const short8*)(vp + (size_t)((cc & 3) * 16) * Ss + kbase + 64 + (cc >> 2) * 32);
      }
    }

    // ---- 4-way merge (plain add), normalize, store ----
    __syncthreads();                      // guard Pmrg reuse across reps
    if (wv) {
#pragma unroll
      for (int qb = 0; qb < 2; ++qb)
#pragma unroll
        for (int ds = 0; ds < 4; ++ds)
#pragma unroll
          for (int r = 0; r < 4; ++r)
            Pmrg[wv - 1][lane][qb * 16 + ds * 4 + r] = oacc[qb][ds][r];
      Pmrg[wv - 1][lane][32] = l2[0];
      Pmrg[wv - 1][lane][33] = l2[1];
    }
    __syncthreads();
    if (!wv) {
#pragma unroll
      for (int qb = 0; qb < 2; ++qb) {
        float l = l2[qb];
#pragma unroll
        for (int w2 = 0; w2 < 3; ++w2) {
#pragma unroll
          for (int ds = 0; ds < 4; ++ds)
#pragma unroll
            for (int r = 0; r < 4; ++r)
              oacc[qb][ds][r] += Pmrg[w2][lane][qb * 16 + ds * 4 + r];
          l += Pmrg[w2][lane][32 + qb];
        }
        l += __shfl_xor(l, 16);
        l += __shfl_xor(l, 32);
        float linv = 1.0f / l;
#pragma unroll
        for (int ds = 0; ds < 4; ++ds)
#pragma unroll
          for (int r = 0; r < 4; ++r)
            Tb[ln * 72 + ds * 16 + g * 4 + r] = bfbits(oacc[qb][ds][r] * linv);
        short8 v0 = *(const short8*)(Tb + ln * 72 + g * 16);
        short8 v1 = *(const short8*)(Tb + ln * 72 + g * 16 + 8);
        size_t oa = ((size_t)b * Ss + q0 + qb * 16 + ln) * Dd + hh * DHh + g * 16;
        *(short8*)(o + oa) = v0;
        *(short8*)(o + oa + 8) = v1;
      }
    }
  }
}

extern "C" void kernel_launch(void* const* d_in, const int* in_sizes, int n_in,
                              void* d_out, int out_size, void* d_ws, size_t ws_size,
                              hipStream_t stream) {
  const float* x     = (const float*)d_in[0];
  const float* gamma = (const float*)d_in[1];
  const float* Wq    = (const float*)d_in[2];
  const float* bq    = (const float*)d_in[3];
  const float* Wk    = (const float*)d_in[4];
  const float* bk    = (const float*)d_in[5];
  const float* Wv    = (const float*)d_in[6];
  const float* bv    = (const float*)d_in[7];
  const float* Wo    = (const float*)d_in[8];
  const float* bo    = (const float*)d_in[9];

  const size_t NX = (size_t)Bb * Ss * Dd;
  const size_t NW = (size_t)Dd * Dd;
  ushort* xb  = (ushort*)d_ws;
  ushort* Wqb = xb + NX;
  ushort* Wkb = Wqb + NW;
  ushort* Wvb = Wkb + NW;
  ushort* Wob = Wvb + NW;
  ushort* qb  = Wob + NW;
  ushort* kb  = qb + NX;
  ushort* vtb = kb + NX;
  ushort* ab  = vtb + NX;

  const int total4 = (int)(NX / 4 + 4 * (NW / 4));
  cvt_all<<<(total4 + 255) / 256, 256, 0, stream>>>(x, Wq, Wk, Wv, Wo, xb);

  qkv_gemm<<<64 * 12, 256, 0, stream>>>(xb, Wqb, Wkb, Wvb, bq, bk, bv, qb, kb, vtb);

  flash7<<<1024, 256, 0, stream>>>(qb, kb, vtb, gamma, ab);

  gemm_out<<<512, 256, 0, stream>>>(ab, Wob, bo, (float*)d_out);
}

// Round 8
// 298.771 us; speedup vs baseline: 2.0078x; 2.0078x over previous
//
#include <hip/hip_runtime.h>
#include <hip/hip_bf16.h>

#define Bb 2
#define Ss 4096
#define Dd 512
#define Hh 8
#define DHh 64

typedef __attribute__((ext_vector_type(8))) short short8;
typedef __attribute__((ext_vector_type(4))) float floatx4;

static __device__ __forceinline__ ushort bfbits(float f) {
  union { __hip_bfloat16 h; ushort u; } cv;
  cv.h = __float2bfloat16(f);
  return cv.u;
}

// pack two fp32 -> two bf16 (truncation; P-weights only, 2^-8 rel err)
static __device__ __forceinline__ unsigned int packhi(float a, float b) {
  union { float f; unsigned int u; } ca, cb; ca.f = a; cb.f = b;
  return (ca.u >> 16) | (cb.u & 0xffff0000u);
}

// ---------------- merged fp32 -> bf16: [x | Wq | Wk | Wv | Wo] ----------------
__global__ void cvt_all(const float* __restrict__ x,
                        const float* __restrict__ w0, const float* __restrict__ w1,
                        const float* __restrict__ w2, const float* __restrict__ w3,
                        ushort* __restrict__ out) {
  const int XN4 = (Bb * Ss * Dd) / 4;
  const int WN4 = (Dd * Dd) / 4;        // 65,536 = 2^16
  int i = blockIdx.x * blockDim.x + threadIdx.x;
  if (i >= XN4 + 4 * WN4) return;
  const float* s; int li;
  if (i < XN4) { s = x; li = i; }
  else {
    int t = i - XN4; int j = t >> 16; li = t & (WN4 - 1);
    s = (j == 0) ? w0 : (j == 1) ? w1 : (j == 2) ? w2 : w3;
  }
  float4 f = ((const float4*)s)[li];
  ushort4 u;
  u.x = bfbits(f.x); u.y = bfbits(f.y); u.z = bfbits(f.z); u.w = bfbits(f.w);
  ((ushort4*)out)[i] = u;
}

// permuted V^T position: key s -> within-64 slot so flash PV A-frags are
// single contiguous 16B loads.
static __device__ __forceinline__ int vperm(int s0) {  // s0 multiple of 4
  int kb = (s0 >> 4) & 3, gq = (s0 >> 2) & 3;
  return (s0 & ~63) | ((kb >> 1) << 5) | (gq << 3) | ((kb & 1) << 2);
}

// ---------------- fused QKV projection GEMM ----------------
#define LDQK(buf, k0)                                                          \
  _Pragma("unroll")                                                            \
  for (int rb = 0; rb < 4; ++rb)                                               \
    af[buf][rb] = *(const short8*)(ap + (size_t)rb * 16 * 512 + (k0));         \
  _Pragma("unroll")                                                            \
  for (int cb = 0; cb < 4; ++cb)                                               \
    bf[buf][cb] = *(const short8*)(bp + (size_t)cb * 16 * 512 + (k0));

__global__ __launch_bounds__(256) void qkv_gemm(
    const ushort* __restrict__ xb,
    const ushort* __restrict__ Wq, const ushort* __restrict__ Wk, const ushort* __restrict__ Wv,
    const float* __restrict__ bq, const float* __restrict__ bk, const float* __restrict__ bv,
    ushort* __restrict__ qo, ushort* __restrict__ ko, ushort* __restrict__ vo)
{
  int mb = blockIdx.x / 12, rest = blockIdx.x % 12;
  int which = rest >> 2, nb = rest & 3;
  const ushort* Bw  = (which == 0) ? Wq : (which == 1) ? Wk : Wv;
  const float* bias = (which == 0) ? bq : (which == 1) ? bk : bv;
  int lane = threadIdx.x & 63, w = threadIdx.x >> 6;
  int wr = w & 1, wc = w >> 1;
  int g = lane >> 4, ln = lane & 15;
  int m0 = mb * 128 + wr * 64;
  int c0 = nb * 128 + wc * 64;
  const ushort* ap = xb + (size_t)(m0 + ln) * 512 + g * 8;
  const ushort* bp = Bw + (size_t)(c0 + ln) * 512 + g * 8;
  floatx4 acc[4][4] = {};
  short8 af[2][4], bf[2][4];
  LDQK(0, 0)
#pragma unroll
  for (int it = 0; it < 16; ++it) {
    int cur = it & 1;
    if (it < 15) { LDQK(cur ^ 1, (it + 1) * 32) }
#pragma unroll
    for (int rb = 0; rb < 4; ++rb)
#pragma unroll
      for (int cb = 0; cb < 4; ++cb)
        acc[rb][cb] = __builtin_amdgcn_mfma_f32_16x16x32_bf16(af[cur][rb], bf[cur][cb], acc[rb][cb], 0, 0, 0);
  }
  // q scale folds 1/sqrt(DH)=0.125 AND log2(e) so flash can use native exp2
  float scale = (which == 0) ? 0.125f * 1.44269504f : 1.0f;
#pragma unroll
  for (int rb = 0; rb < 4; ++rb)
#pragma unroll
    for (int cb = 0; cb < 4; ++cb) {
      int col = c0 + cb * 16 + ln;
      float bv_ = bias[col];
      int hh = col >> 6, dh = col & 63;
      if (which == 2) {
        int i0 = m0 + rb * 16 + g * 4;
        int bI = i0 >> 12, s0 = i0 & (Ss - 1);
        ushort4 pk;
        pk.x = bfbits(acc[rb][cb][0] + bv_);
        pk.y = bfbits(acc[rb][cb][1] + bv_);
        pk.z = bfbits(acc[rb][cb][2] + bv_);
        pk.w = bfbits(acc[rb][cb][3] + bv_);
        *(ushort4*)(vo + (((size_t)bI * Hh + hh) * DHh + dh) * Ss + vperm(s0)) = pk;
      } else {
        ushort* outp = (which == 0) ? qo : ko;
#pragma unroll
        for (int r = 0; r < 4; ++r) {
          int i = m0 + rb * 16 + g * 4 + r;
          int bI = i >> 12, s = i & (Ss - 1);
          outp[(((size_t)bI * Hh + hh) * Ss + s) * DHh + dh] = bfbits((acc[rb][cb][r] + bv_) * scale);
        }
      }
    }
}

// ---------------- output projection GEMM (fp32 out) ----------------
#define LD32(buf, k0)                                                          \
  af[buf][0] = *(const short8*)(ap + (k0));                                    \
  af[buf][1] = *(const short8*)(ap + 16 * 512 + (k0));                         \
  _Pragma("unroll")                                                            \
  for (int ns = 0; ns < 4; ++ns)                                               \
    bfr[buf][ns] = *(const short8*)(bp + (size_t)ns * 16 * 512 + (k0));

__global__ __launch_bounds__(256) void gemm_out(
    const ushort* __restrict__ A, const ushort* __restrict__ Bw,
    const float* __restrict__ bias, float* __restrict__ outp)
{
  int mb = blockIdx.x >> 3, nb = blockIdx.x & 7;
  int lane = threadIdx.x & 63, w = threadIdx.x >> 6;
  int g = lane >> 4, ln = lane & 15;
  int m0 = mb * 128 + w * 32;
  const ushort* ap = A + (size_t)(m0 + ln) * 512 + g * 8;
  const ushort* bp = Bw + (size_t)(nb * 64 + ln) * 512 + g * 8;
  floatx4 acc[2][4] = {};
  short8 af[2][2], bfr[2][4];
  LD32(0, 0)
#pragma unroll
  for (int it = 0; it < 16; ++it) {
    int cur = it & 1;
    if (it < 15) { LD32(cur ^ 1, (it + 1) * 32) }
#pragma unroll
    for (int ns = 0; ns < 4; ++ns) {
      acc[0][ns] = __builtin_amdgcn_mfma_f32_16x16x32_bf16(af[cur][0], bfr[cur][ns], acc[0][ns], 0, 0, 0);
      acc[1][ns] = __builtin_amdgcn_mfma_f32_16x16x32_bf16(af[cur][1], bfr[cur][ns], acc[1][ns], 0, 0, 0);
    }
  }
#pragma unroll
  for (int rb = 0; rb < 2; ++rb)
#pragma unroll
    for (int ns = 0; ns < 4; ++ns) {
      int col = nb * 64 + ns * 16 + ln;
      float bv_ = bias[col];
#pragma unroll
      for (int r = 0; r < 4; ++r)
        outp[(size_t)(m0 + rb * 16 + g * 4 + r) * 512 + col] = acc[rb][ns][r] + bv_;
    }
}

// ---------------- flash attention v8 ----------------
// 3-wave blocks (192 thr): 1024 blocks = 3072 waves = 3 waves/SIMD with NO
// register cap (R4/R7 lesson: this kernel needs ~150 regs; (.,4) bounds force
// spill). Each CU gets exactly 4 identical-work blocks (65 key-tiles each) ->
// zero tail. Waves split keys in thirds, 3-way LDS-add merge.
// No-max softmax in exp2 domain, diag-only masking, trunc-pack P.
__global__ __launch_bounds__(192) void flash8(
    const ushort* __restrict__ q, const ushort* __restrict__ k,
    const ushort* __restrict__ vt, const float* __restrict__ gamma,
    ushort* __restrict__ o)
{
  __shared__ __align__(16) float Pmrg[2][64][34];   // waves 1..2 partial O + l
  __shared__ __align__(16) ushort Tb[16 * 72];      // store-transpose buffer

  int z = blockIdx.x;
  int bh = z & 15, tq = z >> 4;          // tq 0..63
  int b = bh >> 3, hh = bh & 7;
  int tid = threadIdx.x;
  int wv = tid >> 6, lane = tid & 63;    // wv 0..2
  int g = lane >> 4, ln = lane & 15;

  const ushort* kp = k + ((size_t)bh * Ss + ln) * DHh + g * 8;
  const ushort* vp = vt + ((size_t)bh * DHh + ln) * Ss + g * 8;

#pragma unroll 1
  for (int rep = 0; rep < 2; ++rep) {
    int t = rep ? (127 - tq) : tq;
    int q0 = t * 32;
    int nkt = (t >> 1) + 1;
    int ktm = nkt - 1;
    int lo = (nkt * wv) / 3, hi = (nkt * (wv + 1)) / 3;

    const ushort* qp = q + ((size_t)bh * Ss + q0 + ln) * DHh + g * 8;
    short8 qf00 = *(const short8*)qp;
    short8 qf01 = *(const short8*)(qp + 32);
    short8 qf10 = *(const short8*)(qp + 16 * DHh);
    short8 qf11 = *(const short8*)(qp + 16 * DHh + 32);

    int qrow0 = q0 + ln, qrow1 = q0 + 16 + ln;
    float gm0 = gamma[(size_t)b * Ss + qrow0];
    float gm1 = gamma[(size_t)b * Ss + qrow1];
    float l2[2] = {0.0f, 0.0f};
    floatx4 oacc[2][4] = {};

    short8 kfl[4], kfh[4], vf[8];
    int kb0 = lo * 64;
#pragma unroll
    for (int ns = 0; ns < 4; ++ns) {
      kfl[ns] = *(const short8*)(kp + (size_t)(kb0 + ns * 16) * DHh);
      kfh[ns] = *(const short8*)(kp + (size_t)(kb0 + ns * 16) * DHh + 32);
    }
#pragma unroll
    for (int cc = 0; cc < 8; ++cc)
      vf[cc] = *(const short8*)(vp + (size_t)((cc & 3) * 16) * Ss + kb0 + (cc >> 2) * 32);

    for (int kt = lo; kt < hi; ++kt) {
      int kbase = kt * 64;
      // ---- S^T = K . Q^T : 16 MFMAs ----
      float sv[2][16];
#pragma unroll
      for (int ns = 0; ns < 4; ++ns) {
        floatx4 z0 = {}, z1 = {};
        z0 = __builtin_amdgcn_mfma_f32_16x16x32_bf16(kfl[ns], qf00, z0, 0, 0, 0);
        z0 = __builtin_amdgcn_mfma_f32_16x16x32_bf16(kfh[ns], qf01, z0, 0, 0, 0);
        z1 = __builtin_amdgcn_mfma_f32_16x16x32_bf16(kfl[ns], qf10, z1, 0, 0, 0);
        z1 = __builtin_amdgcn_mfma_f32_16x16x32_bf16(kfh[ns], qf11, z1, 0, 0, 0);
#pragma unroll
        for (int r = 0; r < 4; ++r) { sv[0][ns * 4 + r] = z0[r]; sv[1][ns * 4 + r] = z1[r]; }
      }
      // ---- prefetch next K tile ----
      if (kt + 1 < hi) {
        const ushort* kn = kp + (size_t)(kbase + 64) * DHh;
#pragma unroll
        for (int ns = 0; ns < 4; ++ns) {
          kfl[ns] = *(const short8*)(kn + (size_t)(ns * 16) * DHh);
          kfh[ns] = *(const short8*)(kn + (size_t)(ns * 16) * DHh + 32);
        }
      }
      // ---- weights: p = exp2(s) / (1 + gm*max(i-j,0)); s already in log2 ----
      bool last = (kt == ktm);
      short8 pfrag[2][2];
#pragma unroll
      for (int qb = 0; qb < 2; ++qb) {
        int qrow = qb ? qrow1 : qrow0;
        float gm = qb ? gm1 : gm0;
        int db = qrow - kbase - g * 4;     // delta = db - ns*16 - r
        float fd = (float)db;
        float rs = 0.0f;
        if (last) {
#pragma unroll
          for (int e = 0; e < 16; ++e)
            if (db - (e >> 2) * 16 - (e & 3) < 0) sv[qb][e] = -1e30f;
#pragma unroll
          for (int e = 0; e < 16; ++e) {
            float delta = fmaxf(fd - (float)((e >> 2) * 16 + (e & 3)), 0.0f);
            float wt = __builtin_amdgcn_rcpf(fmaf(gm, delta, 1.0f));
            float pv = __builtin_amdgcn_exp2f(sv[qb][e]) * wt;
            rs += pv;
            sv[qb][e] = pv;
          }
        } else {
          // kt < ktm: delta >= 1 always, no clamp/mask needed
#pragma unroll
          for (int e = 0; e < 16; ++e) {
            float delta = fd - (float)((e >> 2) * 16 + (e & 3));
            float wt = __builtin_amdgcn_rcpf(fmaf(gm, delta, 1.0f));
            float pv = __builtin_amdgcn_exp2f(sv[qb][e]) * wt;
            rs += pv;
            sv[qb][e] = pv;
          }
        }
        l2[qb] += rs;
#pragma unroll
        for (int c = 0; c < 2; ++c) {
          uint4 pkd;
          pkd.x = packhi(sv[qb][8 * c + 0], sv[qb][8 * c + 1]);
          pkd.y = packhi(sv[qb][8 * c + 2], sv[qb][8 * c + 3]);
          pkd.z = packhi(sv[qb][8 * c + 4], sv[qb][8 * c + 5]);
          pkd.w = packhi(sv[qb][8 * c + 6], sv[qb][8 * c + 7]);
          pfrag[qb][c] = *(short8*)&pkd;
        }
      }
      // ---- PV: O^T += V^T . P^T : 16 MFMAs ----
#pragma unroll
      for (int c = 0; c < 2; ++c)
#pragma unroll
        for (int ds = 0; ds < 4; ++ds) {
          oacc[0][ds] = __builtin_amdgcn_mfma_f32_16x16x32_bf16(vf[c * 4 + ds], pfrag[0][c], oacc[0][ds], 0, 0, 0);
          oacc[1][ds] = __builtin_amdgcn_mfma_f32_16x16x32_bf16(vf[c * 4 + ds], pfrag[1][c], oacc[1][ds], 0, 0, 0);
        }
      // ---- prefetch next V tile ----
      if (kt + 1 < hi) {
#pragma unroll
        for (int cc = 0; cc < 8; ++cc)
          vf[cc] = *(const short8*)(vp + (size_t)((cc & 3) * 16) * Ss + kbase + 64 + (cc >> 2) * 32);
      }
    }

    // ---- 3-way merge (plain add), normalize, store ----
    __syncthreads();                      // guard Pmrg reuse across reps
    if (wv) {
#pragma unroll
      for (int qb = 0; qb < 2; ++qb)
#pragma unroll
        for (int ds = 0; ds < 4; ++ds)
#pragma unroll
          for (int r = 0; r < 4; ++r)
            Pmrg[wv - 1][lane][qb * 16 + ds * 4 + r] = oacc[qb][ds][r];
      Pmrg[wv - 1][lane][32] = l2[0];
      Pmrg[wv - 1][lane][33] = l2[1];
    }
    __syncthreads();
    if (!wv) {
#pragma unroll
      for (int qb = 0; qb < 2; ++qb) {
        float l = l2[qb];
#pragma unroll
        for (int w2 = 0; w2 < 2; ++w2) {
#pragma unroll
          for (int ds = 0; ds < 4; ++ds)
#pragma unroll
            for (int r = 0; r < 4; ++r)
              oacc[qb][ds][r] += Pmrg[w2][lane][qb * 16 + ds * 4 + r];
          l += Pmrg[w2][lane][32 + qb];
        }
        l += __shfl_xor(l, 16);
        l += __shfl_xor(l, 32);
        float linv = 1.0f / l;
#pragma unroll
        for (int ds = 0; ds < 4; ++ds)
#pragma unroll
          for (int r = 0; r < 4; ++r)
            Tb[ln * 72 + ds * 16 + g * 4 + r] = bfbits(oacc[qb][ds][r] * linv);
        short8 v0 = *(const short8*)(Tb + ln * 72 + g * 16);
        short8 v1 = *(const short8*)(Tb + ln * 72 + g * 16 + 8);
        size_t oa = ((size_t)b * Ss + q0 + qb * 16 + ln) * Dd + hh * DHh + g * 16;
        *(short8*)(o + oa) = v0;
        *(short8*)(o + oa + 8) = v1;
      }
    }
  }
}

extern "C" void kernel_launch(void* const* d_in, const int* in_sizes, int n_in,
                              void* d_out, int out_size, void* d_ws, size_t ws_size,
                              hipStream_t stream) {
  const float* x     = (const float*)d_in[0];
  const float* gamma = (const float*)d_in[1];
  const float* Wq    = (const float*)d_in[2];
  const float* bq    = (const float*)d_in[3];
  const float* Wk    = (const float*)d_in[4];
  const float* bk    = (const float*)d_in[5];
  const float* Wv    = (const float*)d_in[6];
  const float* bv    = (const float*)d_in[7];
  const float* Wo    = (const float*)d_in[8];
  const float* bo    = (const float*)d_in[9];

  const size_t NX = (size_t)Bb * Ss * Dd;
  const size_t NW = (size_t)Dd * Dd;
  ushort* xb  = (ushort*)d_ws;
  ushort* Wqb = xb + NX;
  ushort* Wkb = Wqb + NW;
  ushort* Wvb = Wkb + NW;
  ushort* Wob = Wvb + NW;
  ushort* qb  = Wob + NW;
  ushort* kb  = qb + NX;
  ushort* vtb = kb + NX;
  ushort* ab  = vtb + NX;

  const int total4 = (int)(NX / 4 + 4 * (NW / 4));
  cvt_all<<<(total4 + 255) / 256, 256, 0, stream>>>(x, Wq, Wk, Wv, Wo, xb);

  qkv_gemm<<<64 * 12, 256, 0, stream>>>(xb, Wqb, Wkb, Wvb, bq, bk, bv, qb, kb, vtb);

  flash8<<<1024, 192, 0, stream>>>(qb, kb, vtb, gamma, ab);

  gemm_out<<<512, 256, 0, stream>>>(ab, Wob, bo, (float*)d_out);
}